// Round 2
// baseline (42737.476 us; speedup 1.0000x reference)
//
#include <hip/hip_runtime.h>
#include <hip/hip_bf16.h>
#include <math.h>

#define T_STEPS 4096
#define IN_DIM  512
#define HID     2048
#define LEAK    0.3f

// ---------------------------------------------------------------------------
// Phase 1: P = U @ Win^T + bias, written directly into d_out (T x HID, f32)
// ---------------------------------------------------------------------------
#define GBM 64
#define GBN 64
#define GBK 32

__global__ __launch_bounds__(256) void gemm_p(const float* __restrict__ U,
                                              const float* __restrict__ Win,
                                              const float* __restrict__ bias,
                                              float* __restrict__ P) {
  __shared__ float As[GBM][GBK + 1];
  __shared__ float Bs[GBN][GBK + 1];
  const int bm = blockIdx.x, bn = blockIdx.y;
  const int tid = threadIdx.x;
  const int tx = tid & 15, ty = tid >> 4;

  float acc[4][4];
#pragma unroll
  for (int m = 0; m < 4; ++m)
#pragma unroll
    for (int n = 0; n < 4; ++n) acc[m][n] = 0.f;

  const float* Ub = U + (size_t)bm * GBM * IN_DIM;
  const float* Wb = Win + (size_t)bn * GBN * IN_DIM;

  for (int k0 = 0; k0 < IN_DIM; k0 += GBK) {
#pragma unroll
    for (int v = 0; v < 2; ++v) {
      const int f4 = v * 256 + tid;
      const int row = f4 >> 3;
      const int c4 = (f4 & 7) << 2;
      const float4 a = *(const float4*)(Ub + (size_t)row * IN_DIM + k0 + c4);
      As[row][c4 + 0] = a.x; As[row][c4 + 1] = a.y;
      As[row][c4 + 2] = a.z; As[row][c4 + 3] = a.w;
      const float4 b = *(const float4*)(Wb + (size_t)row * IN_DIM + k0 + c4);
      Bs[row][c4 + 0] = b.x; Bs[row][c4 + 1] = b.y;
      Bs[row][c4 + 2] = b.z; Bs[row][c4 + 3] = b.w;
    }
    __syncthreads();
#pragma unroll 8
    for (int k = 0; k < GBK; ++k) {
      float a[4], b[4];
#pragma unroll
      for (int m = 0; m < 4; ++m) a[m] = As[ty * 4 + m][k];
#pragma unroll
      for (int n = 0; n < 4; ++n) b[n] = Bs[tx * 4 + n][k];
#pragma unroll
      for (int m = 0; m < 4; ++m)
#pragma unroll
        for (int n = 0; n < 4; ++n)
          acc[m][n] = fmaf(a[m], b[n], acc[m][n]);
    }
    __syncthreads();
  }

#pragma unroll
  for (int m = 0; m < 4; ++m) {
    const int gr = bm * GBM + ty * 4 + m;
#pragma unroll
    for (int n = 0; n < 4; ++n) {
      const int gc = bn * GBN + tx * 4 + n;
      P[(size_t)gr * HID + gc] = acc[m][n] + bias[gc];
    }
  }
}

// ---------------------------------------------------------------------------
// Phase 2: persistent recurrence. 64 blocks x 512 threads, W in registers.
// Coherence protocol (no wbl2 ever, one buffer_inv per block per step):
//   - h stores: relaxed agent-scope atomics (sc1 -> LLC, bypass XCD L2)
//   - barrier: per-block flag = step number (relaxed agent store after
//     __syncthreads drains vmcnt); every block polls all 64 flags in
//     parallel (one spin thread per flag, relaxed agent loads)
//   - acquire: one ACQUIRE atomic load per block (emits buffer_inv), then
//     h is read with plain vectorized float4 loads (fresh from LLC)
// ---------------------------------------------------------------------------
#define NB   64                  // blocks
#define NT   512                 // threads per block
#define RPB  (HID / NB)          // 32 rows per block
#define TPR  (NT / RPB)          // 16 threads per row
#define NF4  (HID / (TPR * 4))   // 32 float4 chunks per thread
#define FLAG_STRIDE 16           // 64B-padded flags

__device__ __forceinline__ float fast_tanh(float x) {
  const float e = __expf(2.f * x);
  return 1.f - 2.f / (e + 1.f);
}

__global__ __launch_bounds__(NT, 1) void esn_recur(const float* __restrict__ W,
                                                   float* __restrict__ out,
                                                   unsigned* __restrict__ flags) {
  const int tid = threadIdx.x;
  const int j   = tid & (TPR - 1);       // lane within row
  const int rl  = tid >> 4;              // local row
  const int row = blockIdx.x * RPB + rl;

  // Pin W fragment in registers: W[row][(i*16 + j)*4 .. +3], i = 0..31
  float4 wreg[NF4];
  const float4* wrow = (const float4*)(W + (size_t)row * HID);
#pragma unroll
  for (int i = 0; i < NF4; ++i) wreg[i] = wrow[i * TPR + j];

  // t = 0: h0 = leak * tanh(P0)
  {
    const float pre = out[row];
    const float h = LEAK * fast_tanh(pre);
    if (j == 0)
      __hip_atomic_store(&out[row], h, __ATOMIC_RELAXED, __HIP_MEMORY_SCOPE_AGENT);
  }

  for (int t = 1; t < T_STEPS; ++t) {
    // ---- barrier: wait until all blocks finished step t-1 ----
    __syncthreads();   // drains vmcnt: all this block's sc1 h-stores are at LLC
    if (tid == 0)
      __hip_atomic_store(&flags[blockIdx.x * FLAG_STRIDE], (unsigned)t,
                         __ATOMIC_RELAXED, __HIP_MEMORY_SCOPE_AGENT);
    if (tid < NB) {
      while (__hip_atomic_load(&flags[tid * FLAG_STRIDE],
                               __ATOMIC_RELAXED, __HIP_MEMORY_SCOPE_AGENT) < (unsigned)t) {
      }
    }
    __syncthreads();
    if (tid == 0) {
      // acquire: emits buffer_inv (L1 + XCD L2) so cached reads below are fresh
      (void)__hip_atomic_load(&flags[0], __ATOMIC_ACQUIRE, __HIP_MEMORY_SCOPE_AGENT);
    }
    __syncthreads();

    const float* __restrict__ hprev = out + (size_t)(t - 1) * HID;
    float* __restrict__ ocur = out + (size_t)t * HID;

    const float p  = ocur[row];    // P_t[row] (plain, fresh post-inv)
    const float hp = hprev[row];   // h_{t-1}[row]

    float4 acc = make_float4(0.f, 0.f, 0.f, 0.f);
#pragma unroll
    for (int i = 0; i < NF4; ++i) {
      const float4 hv = *(const float4*)(hprev + (i * TPR + j) * 4);
      acc.x = fmaf(wreg[i].x, hv.x, acc.x);
      acc.y = fmaf(wreg[i].y, hv.y, acc.y);
      acc.z = fmaf(wreg[i].z, hv.z, acc.z);
      acc.w = fmaf(wreg[i].w, hv.w, acc.w);
    }
    float a = (acc.x + acc.y) + (acc.z + acc.w);
    a += __shfl_xor(a, 1, TPR);
    a += __shfl_xor(a, 2, TPR);
    a += __shfl_xor(a, 4, TPR);
    a += __shfl_xor(a, 8, TPR);

    const float pre = p + a;
    const float h = (1.f - LEAK) * hp + LEAK * fast_tanh(pre);
    if (j == 0)
      __hip_atomic_store(&ocur[row], h, __ATOMIC_RELAXED, __HIP_MEMORY_SCOPE_AGENT);
  }
}

// ---------------------------------------------------------------------------
extern "C" void kernel_launch(void* const* d_in, const int* in_sizes, int n_in,
                              void* d_out, int out_size, void* d_ws, size_t ws_size,
                              hipStream_t stream) {
  const float* U    = (const float*)d_in[0];
  const float* Win  = (const float*)d_in[1];
  const float* W    = (const float*)d_in[2];
  const float* bias = (const float*)d_in[3];
  float* out = (float*)d_out;
  unsigned* flags = (unsigned*)d_ws;

  hipMemsetAsync(d_ws, 0, NB * FLAG_STRIDE * sizeof(unsigned), stream);

  dim3 ggrid(T_STEPS / GBM, HID / GBN);
  gemm_p<<<ggrid, 256, 0, stream>>>(U, Win, bias, out);

  esn_recur<<<NB, NT, 0, stream>>>(W, out, flags);
}

// Round 3
// 13441.071 us; speedup vs baseline: 3.1796x; 3.1796x over previous
//
#include <hip/hip_runtime.h>
#include <hip/hip_bf16.h>
#include <math.h>

#define T_STEPS 4096
#define IN_DIM  512
#define HID     2048
#define LEAK    0.3f

// ---------------------------------------------------------------------------
// Phase 1: P = U @ Win^T + bias, written directly into d_out (T x HID, f32)
// ---------------------------------------------------------------------------
#define GBM 64
#define GBN 64
#define GBK 32

__global__ __launch_bounds__(256) void gemm_p(const float* __restrict__ U,
                                              const float* __restrict__ Win,
                                              const float* __restrict__ bias,
                                              float* __restrict__ P) {
  __shared__ float As[GBM][GBK + 1];
  __shared__ float Bs[GBN][GBK + 1];
  const int bm = blockIdx.x, bn = blockIdx.y;
  const int tid = threadIdx.x;
  const int tx = tid & 15, ty = tid >> 4;

  float acc[4][4];
#pragma unroll
  for (int m = 0; m < 4; ++m)
#pragma unroll
    for (int n = 0; n < 4; ++n) acc[m][n] = 0.f;

  const float* Ub = U + (size_t)bm * GBM * IN_DIM;
  const float* Wb = Win + (size_t)bn * GBN * IN_DIM;

  for (int k0 = 0; k0 < IN_DIM; k0 += GBK) {
#pragma unroll
    for (int v = 0; v < 2; ++v) {
      const int f4 = v * 256 + tid;
      const int row = f4 >> 3;
      const int c4 = (f4 & 7) << 2;
      const float4 a = *(const float4*)(Ub + (size_t)row * IN_DIM + k0 + c4);
      As[row][c4 + 0] = a.x; As[row][c4 + 1] = a.y;
      As[row][c4 + 2] = a.z; As[row][c4 + 3] = a.w;
      const float4 b = *(const float4*)(Wb + (size_t)row * IN_DIM + k0 + c4);
      Bs[row][c4 + 0] = b.x; Bs[row][c4 + 1] = b.y;
      Bs[row][c4 + 2] = b.z; Bs[row][c4 + 3] = b.w;
    }
    __syncthreads();
#pragma unroll 8
    for (int k = 0; k < GBK; ++k) {
      float a[4], b[4];
#pragma unroll
      for (int m = 0; m < 4; ++m) a[m] = As[ty * 4 + m][k];
#pragma unroll
      for (int n = 0; n < 4; ++n) b[n] = Bs[tx * 4 + n][k];
#pragma unroll
      for (int m = 0; m < 4; ++m)
#pragma unroll
        for (int n = 0; n < 4; ++n)
          acc[m][n] = fmaf(a[m], b[n], acc[m][n]);
    }
    __syncthreads();
  }

#pragma unroll
  for (int m = 0; m < 4; ++m) {
    const int gr = bm * GBM + ty * 4 + m;
#pragma unroll
    for (int n = 0; n < 4; ++n) {
      const int gc = bn * GBN + tx * 4 + n;
      P[(size_t)gr * HID + gc] = acc[m][n] + bias[gc];
    }
  }
}

// ---------------------------------------------------------------------------
// Phase 2: persistent recurrence with SINGLE-HOP tagged-word exchange.
//   - h published as 64-bit {tag = t+1, f32 bits} via relaxed AGENT-scope
//     8-byte atomic store (bypasses non-coherent XCD L2, lands in LLC).
//   - consumers poll tagged words with relaxed AGENT-scope atomic loads;
//     tag match  =>  value in the same word is valid. No flags, no barrier,
//     no acquire-inv, no fences in the whole loop.
//   - double-buffered slots (ring of 2) are race-free: writing slot t&1
//     requires having observed ALL tags of step t-1, which implies every
//     block finished reading step t-2 (the slot's old content).
//   - fetch phase: 512 threads x 4 words -> LDS (16 KB/block/step from LLC,
//     no redundancy); compute phase reads h from LDS.
//   - own row's h kept in a register (butterfly reduce gives all lanes the
//     full sum), so hp needs no load.
// ---------------------------------------------------------------------------
#define NB   64                  // blocks
#define NT   512                 // threads per block
#define RPB  (HID / NB)          // 32 rows per block
#define TPR  (NT / RPB)          // 16 threads per row
#define NF4  (HID / (TPR * 4))   // 32 float4 chunks per thread

__device__ __forceinline__ float fast_tanh(float x) {
  const float e = __expf(2.f * x);
  return 1.f - 2.f / (e + 1.f);
}

__device__ __forceinline__ void pub(unsigned long long* p, unsigned tag, float v) {
  const unsigned long long w =
      ((unsigned long long)tag << 32) | (unsigned long long)__float_as_uint(v);
  __hip_atomic_store(p, w, __ATOMIC_RELAXED, __HIP_MEMORY_SCOPE_AGENT);
}

__global__ __launch_bounds__(NT, 1) void esn_recur(const float* __restrict__ W,
                                                   float* __restrict__ out,
                                                   unsigned long long* __restrict__ slots) {
  const int tid = threadIdx.x;
  const int j   = tid & (TPR - 1);       // lane within row
  const int rl  = tid >> 4;              // local row
  const int row = blockIdx.x * RPB + rl;

  __shared__ float hs[HID];              // 8 KB staging for h_{t-1}

  // Pin W fragment in registers: chunk c = i*16 + j, floats c*4..c*4+3
  float4 wreg[NF4];
  const float4* wrow = (const float4*)(W + (size_t)row * HID);
#pragma unroll
  for (int i = 0; i < NF4; ++i) wreg[i] = wrow[i * TPR + j];

  // ---- t = 0: h0 = leak * tanh(P0), publish with tag 1 into slot 0 ----
  float hp = LEAK * fast_tanh(out[row]); // all 16 lanes compute identically
  if (j == 0) {
    out[row] = hp;
    pub(&slots[row], 1u, hp);
  }

  for (int t = 1; t < T_STEPS; ++t) {
    float* __restrict__ ocur = out + (size_t)t * HID;
    const float p = ocur[row];           // issue early; hides under the spin

    // ---- fetch phase: poll 4 tagged words, stage into LDS ----
    unsigned long long* __restrict__ src = slots + (size_t)((t - 1) & 1) * HID;
    const unsigned expect = (unsigned)t; // tag of h_{t-1} is (t-1)+1 = t
    float4 hv4;
#pragma unroll
    for (int q = 0; q < 4; ++q) {
      unsigned long long w;
      do {
        w = __hip_atomic_load(&src[tid * 4 + q], __ATOMIC_RELAXED,
                              __HIP_MEMORY_SCOPE_AGENT);
      } while ((unsigned)(w >> 32) != expect);
      ((float*)&hv4)[q] = __uint_as_float((unsigned)(w & 0xffffffffu));
    }
    __syncthreads();                     // prior step's LDS reads are done
    *(float4*)&hs[tid * 4] = hv4;
    __syncthreads();                     // h_{t-1} staged

    // ---- compute phase ----
    float4 acc = make_float4(0.f, 0.f, 0.f, 0.f);
#pragma unroll
    for (int i = 0; i < NF4; ++i) {
      const float4 hv = *(const float4*)&hs[(i * TPR + j) * 4];
      acc.x = fmaf(wreg[i].x, hv.x, acc.x);
      acc.y = fmaf(wreg[i].y, hv.y, acc.y);
      acc.z = fmaf(wreg[i].z, hv.z, acc.z);
      acc.w = fmaf(wreg[i].w, hv.w, acc.w);
    }
    float a = (acc.x + acc.y) + (acc.z + acc.w);
    a += __shfl_xor(a, 1, TPR);
    a += __shfl_xor(a, 2, TPR);
    a += __shfl_xor(a, 4, TPR);
    a += __shfl_xor(a, 8, TPR);          // all lanes hold the full dot

    const float h = (1.f - LEAK) * hp + LEAK * fast_tanh(p + a);
    hp = h;
    if (j == 0) {
      ocur[row] = h;                     // plain cached store (own XCD only)
      pub(&slots[(size_t)(t & 1) * HID + row], (unsigned)(t + 1), h);
    }
  }
}

// ---------------------------------------------------------------------------
extern "C" void kernel_launch(void* const* d_in, const int* in_sizes, int n_in,
                              void* d_out, int out_size, void* d_ws, size_t ws_size,
                              hipStream_t stream) {
  const float* U    = (const float*)d_in[0];
  const float* Win  = (const float*)d_in[1];
  const float* W    = (const float*)d_in[2];
  const float* bias = (const float*)d_in[3];
  float* out = (float*)d_out;
  unsigned long long* slots = (unsigned long long*)d_ws;

  // wipe tags (also clears stale tags between graph replays); tag 0 is
  // never a valid tag (tags are t+1 >= 1), so memset can't false-match
  hipMemsetAsync(d_ws, 0, 2 * HID * sizeof(unsigned long long), stream);

  dim3 ggrid(T_STEPS / GBM, HID / GBN);
  gemm_p<<<ggrid, 256, 0, stream>>>(U, Win, bias, out);

  esn_recur<<<NB, NT, 0, stream>>>(W, out, slots);
}